// Round 1
// baseline (1816.633 us; speedup 1.0000x reference)
//
#include <hip/hip_runtime.h>

#define N_NODES 50000
#define N_EDGES 600000
#define DIM 128

#define TM 32
#define SA_STRIDE (DIM + 4)     // 132 floats
#define SH_STRIDE (256 + 4)     // 260 floats

// out[i,:] = x[i,:] + e1[4,:] + e2[0,:]
__global__ __launch_bounds__(256) void init_out_kernel(
    const float* __restrict__ x, const float* __restrict__ e1,
    const float* __restrict__ e2, float* __restrict__ out)
{
    int idx = blockIdx.x * 256 + threadIdx.x;      // over N*D/4
    const int total = N_NODES * (DIM / 4);
    if (idx >= total) return;
    int d4 = idx & 31;                              // DIM/4 == 32
    float4 xv = reinterpret_cast<const float4*>(x)[idx];
    float4 av = reinterpret_cast<const float4*>(e1 + 4 * DIM)[d4];
    float4 bv = reinterpret_cast<const float4*>(e2)[d4];
    float4 o;
    o.x = xv.x + av.x + bv.x;
    o.y = xv.y + av.y + bv.y;
    o.z = xv.z + av.z + bv.z;
    o.w = xv.w + av.w + bv.w;
    reinterpret_cast<float4*>(out)[idx] = o;
}

// out[row[e],:] += x[col[e],:] + e1[a0,:] + e2[a1,:]   (32 threads per edge)
__global__ __launch_bounds__(256) void scatter_kernel(
    const float* __restrict__ x, const int* __restrict__ eidx,
    const int* __restrict__ eattr, const float* __restrict__ e1,
    const float* __restrict__ e2, float* __restrict__ out)
{
    int t = blockIdx.x * 256 + threadIdx.x;
    int e = t >> 5;
    if (e >= N_EDGES) return;
    int l = t & 31;
    int row = eidx[e];
    int col = eidx[N_EDGES + e];
    int a0 = eattr[2 * e];
    int a1 = eattr[2 * e + 1];
    float4 xv = reinterpret_cast<const float4*>(x  + (size_t)col * DIM)[l];
    float4 v1 = reinterpret_cast<const float4*>(e1 + (size_t)a0 * DIM)[l];
    float4 v2 = reinterpret_cast<const float4*>(e2 + (size_t)a1 * DIM)[l];
    float* o = out + (size_t)row * DIM + l * 4;
    atomicAdd(o + 0, xv.x + v1.x + v2.x);
    atomicAdd(o + 1, xv.y + v1.y + v2.y);
    atomicAdd(o + 2, xv.z + v1.z + v2.z);
    atomicAdd(o + 3, xv.w + v1.w + v2.w);
}

// Y = relu(A @ W1^T + b1) @ W2^T + b2, fused per 32-row tile.
__global__ __launch_bounds__(256) void mlp_kernel(
    const float* __restrict__ A, const float* __restrict__ W1,
    const float* __restrict__ b1, const float* __restrict__ W2,
    const float* __restrict__ b2, float* __restrict__ Y)
{
    __shared__ float sA[TM * SA_STRIDE];   // ~16.9 KB
    __shared__ float sH[TM * SH_STRIDE];   // ~33.3 KB
    int t = threadIdx.x;
    int base = blockIdx.x * TM;

    // load A tile (32 rows x 128 floats), float4-coalesced
    for (int i = t; i < TM * 32; i += 256) {
        int r = i >> 5, c4 = i & 31;
        int row = base + r;
        float4 v = make_float4(0.f, 0.f, 0.f, 0.f);
        if (row < N_NODES)
            v = reinterpret_cast<const float4*>(A)[(size_t)row * 32 + c4];
        *reinterpret_cast<float4*>(&sA[r * SA_STRIDE + c4 * 4]) = v;
    }
    __syncthreads();

    int tj  = t & 15;       // 0..15
    int tmg = t >> 4;       // 0..15
    int m0  = tmg * 2;

    // ---- stage 1: h = relu(A @ W1^T + b1), h kept in LDS ----
    for (int jc = 0; jc < 4; ++jc) {
        int j0 = jc * 64 + tj * 4;              // output column base (4 cols)
        float acc0[4] = {0.f, 0.f, 0.f, 0.f};
        float acc1[4] = {0.f, 0.f, 0.f, 0.f};
        #pragma unroll 8
        for (int d4 = 0; d4 < 32; ++d4) {
            float4 a0 = *reinterpret_cast<const float4*>(&sA[m0 * SA_STRIDE + d4 * 4]);
            float4 a1 = *reinterpret_cast<const float4*>(&sA[(m0 + 1) * SA_STRIDE + d4 * 4]);
            #pragma unroll
            for (int q = 0; q < 4; ++q) {
                float4 w = reinterpret_cast<const float4*>(W1 + (size_t)(j0 + q) * DIM)[d4];
                acc0[q] += a0.x * w.x + a0.y * w.y + a0.z * w.z + a0.w * w.w;
                acc1[q] += a1.x * w.x + a1.y * w.y + a1.z * w.z + a1.w * w.w;
            }
        }
        float4 h0, h1;
        h0.x = fmaxf(acc0[0] + b1[j0 + 0], 0.f);
        h0.y = fmaxf(acc0[1] + b1[j0 + 1], 0.f);
        h0.z = fmaxf(acc0[2] + b1[j0 + 2], 0.f);
        h0.w = fmaxf(acc0[3] + b1[j0 + 3], 0.f);
        h1.x = fmaxf(acc1[0] + b1[j0 + 0], 0.f);
        h1.y = fmaxf(acc1[1] + b1[j0 + 1], 0.f);
        h1.z = fmaxf(acc1[2] + b1[j0 + 2], 0.f);
        h1.w = fmaxf(acc1[3] + b1[j0 + 3], 0.f);
        *reinterpret_cast<float4*>(&sH[m0 * SH_STRIDE + j0]) = h0;
        *reinterpret_cast<float4*>(&sH[(m0 + 1) * SH_STRIDE + j0]) = h1;
    }
    __syncthreads();

    // ---- stage 2: Y = h @ W2^T + b2 ----
    int tdc = t & 15;
    for (int ch = 0; ch < 4; ++ch) {
        int dc0 = ch * 32 + tdc * 2;            // 2 output cols
        float acc00 = 0.f, acc01 = 0.f, acc10 = 0.f, acc11 = 0.f;
        #pragma unroll 8
        for (int k4 = 0; k4 < 64; ++k4) {
            float4 h0 = *reinterpret_cast<const float4*>(&sH[m0 * SH_STRIDE + k4 * 4]);
            float4 h1 = *reinterpret_cast<const float4*>(&sH[(m0 + 1) * SH_STRIDE + k4 * 4]);
            float4 wa = reinterpret_cast<const float4*>(W2 + (size_t)(dc0 + 0) * 256)[k4];
            float4 wb = reinterpret_cast<const float4*>(W2 + (size_t)(dc0 + 1) * 256)[k4];
            acc00 += h0.x * wa.x + h0.y * wa.y + h0.z * wa.z + h0.w * wa.w;
            acc01 += h0.x * wb.x + h0.y * wb.y + h0.z * wb.z + h0.w * wb.w;
            acc10 += h1.x * wa.x + h1.y * wa.y + h1.z * wa.z + h1.w * wa.w;
            acc11 += h1.x * wb.x + h1.y * wb.y + h1.z * wb.z + h1.w * wb.w;
        }
        float bza = b2[dc0 + 0], bzb = b2[dc0 + 1];
        #pragma unroll
        for (int p = 0; p < 2; ++p) {
            int row = base + m0 + p;
            if (row < N_NODES) {
                float2 v;
                v.x = (p == 0 ? acc00 : acc10) + bza;
                v.y = (p == 0 ? acc01 : acc11) + bzb;
                *reinterpret_cast<float2*>(&Y[(size_t)row * DIM + dc0]) = v;
            }
        }
    }
}

extern "C" void kernel_launch(void* const* d_in, const int* in_sizes, int n_in,
                              void* d_out, int out_size, void* d_ws, size_t ws_size,
                              hipStream_t stream)
{
    const float* x   = (const float*)d_in[0];
    const int*  eidx = (const int*)d_in[1];
    const int*  eattr= (const int*)d_in[2];
    const float* W1  = (const float*)d_in[3];
    const float* b1  = (const float*)d_in[4];
    const float* W2  = (const float*)d_in[5];
    const float* b2  = (const float*)d_in[6];
    const float* e1  = (const float*)d_in[7];
    const float* e2  = (const float*)d_in[8];
    float* Y   = (float*)d_out;
    float* out = (float*)d_ws;   // N*D fp32 aggregate = 25.6 MB

    init_out_kernel<<<(N_NODES * 32 + 255) / 256, 256, 0, stream>>>(x, e1, e2, out);
    scatter_kernel<<<(N_EDGES * 32 + 255) / 256, 256, 0, stream>>>(x, eidx, eattr, e1, e2, out);
    mlp_kernel<<<(N_NODES + TM - 1) / TM, 256, 0, stream>>>(out, W1, b1, W2, b2, Y);
}

// Round 2
// 913.691 us; speedup vs baseline: 1.9882x; 1.9882x over previous
//
#include <hip/hip_runtime.h>

#define N_NODES 50000
#define N_EDGES 600000
#define DIM 128

#define NB_SCAN 196            // ceil(50000/256)
#define GRID_E 2344            // ceil(600000/256)

#define TM 32
#define SA_STRIDE (DIM + 4)     // 132 floats
#define SH_STRIDE (256 + 4)     // 260 floats

// ---- ws layout (bytes) ----
// [0, 12.8MB)            : out_bf16  N*D ushort
// [12800000, +200000)    : off[50000] int (deg -> start -> end offsets)
// [13000000, +1024)      : bs[256] int (block sums)
// [13001024, +2.4MB)     : perm[600000] u32 packed edges
#define WS_OFF_OFF   12800000
#define WS_BS_OFF    13000000
#define WS_PERM_OFF  13001024

__device__ __forceinline__ unsigned short f2bf(float f) {
    unsigned int b = __float_as_uint(f);
    b += 0x7FFFu + ((b >> 16) & 1u);     // round-to-nearest-even
    return (unsigned short)(b >> 16);
}

__global__ __launch_bounds__(256) void zero_off_kernel(int* __restrict__ off) {
    int i = blockIdx.x * 256 + threadIdx.x;
    if (i < N_NODES) off[i] = 0;
}

__global__ __launch_bounds__(256) void hist_kernel(
    const int* __restrict__ eidx, int* __restrict__ off)
{
    int e = blockIdx.x * 256 + threadIdx.x;
    if (e < N_EDGES) atomicAdd(&off[eidx[e]], 1);
}

// per-block sums of off -> bs[b]
__global__ __launch_bounds__(256) void block_sum_kernel(
    const int* __restrict__ off, int* __restrict__ bs)
{
    __shared__ int s[256];
    int t = threadIdx.x;
    int i = blockIdx.x * 256 + t;
    s[t] = (i < N_NODES) ? off[i] : 0;
    __syncthreads();
    for (int o = 128; o > 0; o >>= 1) {
        if (t < o) s[t] += s[t + o];
        __syncthreads();
    }
    if (t == 0) bs[blockIdx.x] = s[0];
}

// inclusive scan of bs[0..NB_SCAN) in-place (single block)
__global__ __launch_bounds__(256) void scan_bs_kernel(int* __restrict__ bs) {
    __shared__ int s[256];
    int t = threadIdx.x;
    s[t] = (t < NB_SCAN) ? bs[t] : 0;
    __syncthreads();
    for (int o = 1; o < 256; o <<= 1) {
        int u = (t >= o) ? s[t - o] : 0;
        __syncthreads();
        s[t] += u;
        __syncthreads();
    }
    if (t < NB_SCAN) bs[t] = s[t];
}

// off[i] = global exclusive prefix (start offsets)
__global__ __launch_bounds__(256) void scan_off_kernel(
    int* __restrict__ off, const int* __restrict__ bs)
{
    __shared__ int s[256];
    int t = threadIdx.x;
    int b = blockIdx.x;
    int i = b * 256 + t;
    int v = (i < N_NODES) ? off[i] : 0;
    s[t] = v;
    __syncthreads();
    for (int o = 1; o < 256; o <<= 1) {
        int u = (t >= o) ? s[t - o] : 0;
        __syncthreads();
        s[t] += u;
        __syncthreads();
    }
    int ex = (t ? s[t - 1] : 0) + (b ? bs[b - 1] : 0);
    if (i < N_NODES) off[i] = ex;
}

// place edges grouped by destination row; off becomes END offsets
__global__ __launch_bounds__(256) void place_kernel(
    const int* __restrict__ eidx, const int* __restrict__ eattr,
    int* __restrict__ off, unsigned int* __restrict__ perm)
{
    int e = blockIdx.x * 256 + threadIdx.x;
    if (e >= N_EDGES) return;
    int row = eidx[e];
    unsigned int col = (unsigned int)eidx[N_EDGES + e];
    unsigned int a0  = (unsigned int)eattr[2 * e];
    unsigned int a1  = (unsigned int)eattr[2 * e + 1];
    int pos = atomicAdd(&off[row], 1);
    perm[pos] = col | (a0 << 16) | (a1 << 19);
}

// per node: acc = x[i]+e1[4]+e2[0] + sum over its edges of x[col]+e1[a0]+e2[a1]
// 32 lanes per node, float4 per lane; write bf16 row once.
__global__ __launch_bounds__(256) void gather_kernel(
    const float* __restrict__ x, const unsigned int* __restrict__ perm,
    const int* __restrict__ off, const float* __restrict__ e1,
    const float* __restrict__ e2, unsigned short* __restrict__ outb)
{
    int gid = blockIdx.x * 256 + threadIdx.x;
    int g = gid >> 5;                 // node
    if (g >= N_NODES) return;
    int l = gid & 31;                 // float4 lane within row

    const float4* x4  = reinterpret_cast<const float4*>(x);
    const float4* e14 = reinterpret_cast<const float4*>(e1);
    const float4* e24 = reinterpret_cast<const float4*>(e2);

    float4 a  = x4[(size_t)g * 32 + l];
    float4 s1 = e14[4 * 32 + l];      // e1[SELF_LOOP_TYPE=4]
    float4 s2 = e24[l];               // e2[0]
    float accx = a.x + s1.x + s2.x;
    float accy = a.y + s1.y + s2.y;
    float accz = a.z + s1.z + s2.z;
    float accw = a.w + s1.w + s2.w;

    int start = g ? off[g - 1] : 0;
    int end   = off[g];
    for (int e = start; e < end; ++e) {
        unsigned int u = perm[e];
        int col = (int)(u & 0xFFFFu);
        int a0  = (int)((u >> 16) & 7u);
        int a1  = (int)(u >> 19);
        float4 xv = x4[(size_t)col * 32 + l];
        float4 v1 = e14[a0 * 32 + l];
        float4 v2 = e24[a1 * 32 + l];
        accx += xv.x + v1.x + v2.x;
        accy += xv.y + v1.y + v2.y;
        accz += xv.z + v1.z + v2.z;
        accw += xv.w + v1.w + v2.w;
    }

    ushort4 o;
    o.x = f2bf(accx); o.y = f2bf(accy); o.z = f2bf(accz); o.w = f2bf(accw);
    reinterpret_cast<ushort4*>(outb)[(size_t)g * 32 + l] = o;
}

// Y = relu(A @ W1^T + b1) @ W2^T + b2, fused per 32-row tile. A is bf16.
__global__ __launch_bounds__(256) void mlp_kernel(
    const unsigned short* __restrict__ A, const float* __restrict__ W1,
    const float* __restrict__ b1, const float* __restrict__ W2,
    const float* __restrict__ b2, float* __restrict__ Y)
{
    __shared__ float sA[TM * SA_STRIDE];   // ~16.9 KB
    __shared__ float sH[TM * SH_STRIDE];   // ~33.3 KB
    int t = threadIdx.x;
    int base = blockIdx.x * TM;

    // load A tile (32 rows x 128 bf16), convert to f32 in LDS
    for (int i = t; i < TM * 32; i += 256) {
        int r = i >> 5, c4 = i & 31;
        int row = base + r;
        float4 v = make_float4(0.f, 0.f, 0.f, 0.f);
        if (row < N_NODES) {
            ushort4 u = reinterpret_cast<const ushort4*>(A)[(size_t)row * 32 + c4];
            v.x = __uint_as_float((unsigned int)u.x << 16);
            v.y = __uint_as_float((unsigned int)u.y << 16);
            v.z = __uint_as_float((unsigned int)u.z << 16);
            v.w = __uint_as_float((unsigned int)u.w << 16);
        }
        *reinterpret_cast<float4*>(&sA[r * SA_STRIDE + c4 * 4]) = v;
    }
    __syncthreads();

    int tj  = t & 15;       // 0..15
    int tmg = t >> 4;       // 0..15
    int m0  = tmg * 2;

    // ---- stage 1: h = relu(A @ W1^T + b1), h kept in LDS ----
    for (int jc = 0; jc < 4; ++jc) {
        int j0 = jc * 64 + tj * 4;
        float acc0[4] = {0.f, 0.f, 0.f, 0.f};
        float acc1[4] = {0.f, 0.f, 0.f, 0.f};
        #pragma unroll 8
        for (int d4 = 0; d4 < 32; ++d4) {
            float4 a0 = *reinterpret_cast<const float4*>(&sA[m0 * SA_STRIDE + d4 * 4]);
            float4 a1 = *reinterpret_cast<const float4*>(&sA[(m0 + 1) * SA_STRIDE + d4 * 4]);
            #pragma unroll
            for (int q = 0; q < 4; ++q) {
                float4 w = reinterpret_cast<const float4*>(W1 + (size_t)(j0 + q) * DIM)[d4];
                acc0[q] += a0.x * w.x + a0.y * w.y + a0.z * w.z + a0.w * w.w;
                acc1[q] += a1.x * w.x + a1.y * w.y + a1.z * w.z + a1.w * w.w;
            }
        }
        float4 h0, h1;
        h0.x = fmaxf(acc0[0] + b1[j0 + 0], 0.f);
        h0.y = fmaxf(acc0[1] + b1[j0 + 1], 0.f);
        h0.z = fmaxf(acc0[2] + b1[j0 + 2], 0.f);
        h0.w = fmaxf(acc0[3] + b1[j0 + 3], 0.f);
        h1.x = fmaxf(acc1[0] + b1[j0 + 0], 0.f);
        h1.y = fmaxf(acc1[1] + b1[j0 + 1], 0.f);
        h1.z = fmaxf(acc1[2] + b1[j0 + 2], 0.f);
        h1.w = fmaxf(acc1[3] + b1[j0 + 3], 0.f);
        *reinterpret_cast<float4*>(&sH[m0 * SH_STRIDE + j0]) = h0;
        *reinterpret_cast<float4*>(&sH[(m0 + 1) * SH_STRIDE + j0]) = h1;
    }
    __syncthreads();

    // ---- stage 2: Y = h @ W2^T + b2 ----
    int tdc = t & 15;
    for (int ch = 0; ch < 4; ++ch) {
        int dc0 = ch * 32 + tdc * 2;
        float acc00 = 0.f, acc01 = 0.f, acc10 = 0.f, acc11 = 0.f;
        #pragma unroll 8
        for (int k4 = 0; k4 < 64; ++k4) {
            float4 h0 = *reinterpret_cast<const float4*>(&sH[m0 * SH_STRIDE + k4 * 4]);
            float4 h1 = *reinterpret_cast<const float4*>(&sH[(m0 + 1) * SH_STRIDE + k4 * 4]);
            float4 wa = reinterpret_cast<const float4*>(W2 + (size_t)(dc0 + 0) * 256)[k4];
            float4 wb = reinterpret_cast<const float4*>(W2 + (size_t)(dc0 + 1) * 256)[k4];
            acc00 += h0.x * wa.x + h0.y * wa.y + h0.z * wa.z + h0.w * wa.w;
            acc01 += h0.x * wb.x + h0.y * wb.y + h0.z * wb.z + h0.w * wb.w;
            acc10 += h1.x * wa.x + h1.y * wa.y + h1.z * wa.z + h1.w * wa.w;
            acc11 += h1.x * wb.x + h1.y * wb.y + h1.z * wb.z + h1.w * wb.w;
        }
        float bza = b2[dc0 + 0], bzb = b2[dc0 + 1];
        #pragma unroll
        for (int p = 0; p < 2; ++p) {
            int row = base + m0 + p;
            if (row < N_NODES) {
                float2 v;
                v.x = (p == 0 ? acc00 : acc10) + bza;
                v.y = (p == 0 ? acc01 : acc11) + bzb;
                *reinterpret_cast<float2*>(&Y[(size_t)row * DIM + dc0]) = v;
            }
        }
    }
}

extern "C" void kernel_launch(void* const* d_in, const int* in_sizes, int n_in,
                              void* d_out, int out_size, void* d_ws, size_t ws_size,
                              hipStream_t stream)
{
    const float* x   = (const float*)d_in[0];
    const int*  eidx = (const int*)d_in[1];
    const int*  eattr= (const int*)d_in[2];
    const float* W1  = (const float*)d_in[3];
    const float* b1  = (const float*)d_in[4];
    const float* W2  = (const float*)d_in[5];
    const float* b2  = (const float*)d_in[6];
    const float* e1  = (const float*)d_in[7];
    const float* e2  = (const float*)d_in[8];
    float* Y = (float*)d_out;

    char* ws = (char*)d_ws;
    unsigned short* outb = (unsigned short*)ws;                    // N*D bf16
    int* off             = (int*)(ws + WS_OFF_OFF);                // N ints
    int* bs              = (int*)(ws + WS_BS_OFF);                 // 256 ints
    unsigned int* perm   = (unsigned int*)(ws + WS_PERM_OFF);      // E u32

    zero_off_kernel <<<NB_SCAN, 256, 0, stream>>>(off);
    hist_kernel     <<<GRID_E,  256, 0, stream>>>(eidx, off);
    block_sum_kernel<<<NB_SCAN, 256, 0, stream>>>(off, bs);
    scan_bs_kernel  <<<1,       256, 0, stream>>>(bs);
    scan_off_kernel <<<NB_SCAN, 256, 0, stream>>>(off, bs);
    place_kernel    <<<GRID_E,  256, 0, stream>>>(eidx, eattr, off, perm);
    gather_kernel   <<<(N_NODES * 32 + 255) / 256, 256, 0, stream>>>(x, perm, off, e1, e2, outb);
    mlp_kernel      <<<(N_NODES + TM - 1) / TM, 256, 0, stream>>>(outb, W1, b1, W2, b2, Y);
}

// Round 3
// 195.508 us; speedup vs baseline: 9.2919x; 4.6734x over previous
//
#include <hip/hip_runtime.h>

#define N_NODES 50000
#define N_EDGES 600000
#define DIM 128

#define NB_SCAN 196            // ceil(50000/256)
#define GRID_E 2344            // ceil(600000/256)

// ---- ws layout (bytes) ----
#define WS_OFF_OFF   12800000   // off[50000] int
#define WS_BS_OFF    13000000   // bs[256] int
#define WS_PERM_OFF  13001024   // perm[600000] u32
#define WS_W1B_OFF   15500000   // w1b [256*128] bf16 (64 KB)
#define WS_W2B_OFF   15565536   // w2b [128*256] bf16 (64 KB)

typedef __attribute__((ext_vector_type(8))) short bf16x8;
typedef __attribute__((ext_vector_type(4))) float f32x4;

__device__ __forceinline__ unsigned short f2bf(float f) {
    unsigned int b = __float_as_uint(f);
    b += 0x7FFFu + ((b >> 16) & 1u);     // round-to-nearest-even
    return (unsigned short)(b >> 16);
}

__global__ __launch_bounds__(256) void zero_off_kernel(int* __restrict__ off) {
    int i = blockIdx.x * 256 + threadIdx.x;
    if (i < N_NODES) off[i] = 0;
}

__global__ __launch_bounds__(256) void hist_kernel(
    const int* __restrict__ eidx, int* __restrict__ off)
{
    int e = blockIdx.x * 256 + threadIdx.x;
    if (e < N_EDGES) atomicAdd(&off[eidx[e]], 1);
}

__global__ __launch_bounds__(256) void block_sum_kernel(
    const int* __restrict__ off, int* __restrict__ bs)
{
    __shared__ int s[256];
    int t = threadIdx.x;
    int i = blockIdx.x * 256 + t;
    s[t] = (i < N_NODES) ? off[i] : 0;
    __syncthreads();
    for (int o = 128; o > 0; o >>= 1) {
        if (t < o) s[t] += s[t + o];
        __syncthreads();
    }
    if (t == 0) bs[blockIdx.x] = s[0];
}

__global__ __launch_bounds__(256) void scan_bs_kernel(int* __restrict__ bs) {
    __shared__ int s[256];
    int t = threadIdx.x;
    s[t] = (t < NB_SCAN) ? bs[t] : 0;
    __syncthreads();
    for (int o = 1; o < 256; o <<= 1) {
        int u = (t >= o) ? s[t - o] : 0;
        __syncthreads();
        s[t] += u;
        __syncthreads();
    }
    if (t < NB_SCAN) bs[t] = s[t];
}

__global__ __launch_bounds__(256) void scan_off_kernel(
    int* __restrict__ off, const int* __restrict__ bs)
{
    __shared__ int s[256];
    int t = threadIdx.x;
    int b = blockIdx.x;
    int i = b * 256 + t;
    int v = (i < N_NODES) ? off[i] : 0;
    s[t] = v;
    __syncthreads();
    for (int o = 1; o < 256; o <<= 1) {
        int u = (t >= o) ? s[t - o] : 0;
        __syncthreads();
        s[t] += u;
        __syncthreads();
    }
    int ex = (t ? s[t - 1] : 0) + (b ? bs[b - 1] : 0);
    if (i < N_NODES) off[i] = ex;
}

__global__ __launch_bounds__(256) void place_kernel(
    const int* __restrict__ eidx, const int* __restrict__ eattr,
    int* __restrict__ off, unsigned int* __restrict__ perm)
{
    int e = blockIdx.x * 256 + threadIdx.x;
    if (e >= N_EDGES) return;
    int row = eidx[e];
    unsigned int col = (unsigned int)eidx[N_EDGES + e];
    unsigned int a0  = (unsigned int)eattr[2 * e];
    unsigned int a1  = (unsigned int)eattr[2 * e + 1];
    int pos = atomicAdd(&off[row], 1);
    perm[pos] = col | (a0 << 16) | (a1 << 19);
}

__global__ __launch_bounds__(256) void gather_kernel(
    const float* __restrict__ x, const unsigned int* __restrict__ perm,
    const int* __restrict__ off, const float* __restrict__ e1,
    const float* __restrict__ e2, unsigned short* __restrict__ outb)
{
    int gid = blockIdx.x * 256 + threadIdx.x;
    int g = gid >> 5;                 // node
    if (g >= N_NODES) return;
    int l = gid & 31;                 // float4 lane within row

    const float4* x4  = reinterpret_cast<const float4*>(x);
    const float4* e14 = reinterpret_cast<const float4*>(e1);
    const float4* e24 = reinterpret_cast<const float4*>(e2);

    float4 a  = x4[(size_t)g * 32 + l];
    float4 s1 = e14[4 * 32 + l];      // e1[SELF_LOOP_TYPE=4]
    float4 s2 = e24[l];               // e2[0]
    float accx = a.x + s1.x + s2.x;
    float accy = a.y + s1.y + s2.y;
    float accz = a.z + s1.z + s2.z;
    float accw = a.w + s1.w + s2.w;

    int start = g ? off[g - 1] : 0;
    int end   = off[g];
    for (int e = start; e < end; ++e) {
        unsigned int u = perm[e];
        int col = (int)(u & 0xFFFFu);
        int a0  = (int)((u >> 16) & 7u);
        int a1  = (int)(u >> 19);
        float4 xv = x4[(size_t)col * 32 + l];
        float4 v1 = e14[a0 * 32 + l];
        float4 v2 = e24[a1 * 32 + l];
        accx += xv.x + v1.x + v2.x;
        accy += xv.y + v1.y + v2.y;
        accz += xv.z + v1.z + v2.z;
        accw += xv.w + v1.w + v2.w;
    }

    ushort4 o;
    o.x = f2bf(accx); o.y = f2bf(accy); o.z = f2bf(accz); o.w = f2bf(accw);
    reinterpret_cast<ushort4*>(outb)[(size_t)g * 32 + l] = o;
}

__global__ __launch_bounds__(256) void cvt_w_kernel(
    const float* __restrict__ W, unsigned short* __restrict__ Wb, int n)
{
    int i = blockIdx.x * 256 + threadIdx.x;
    if (i < n) Wb[i] = f2bf(W[i]);
}

// Fused MLP via MFMA: Y = relu(A @ W1^T + b1) @ W2^T + b2
// A [N,128] bf16; W1 [256,128] bf16; W2 [128,256] bf16. 64 rows/block, 4 waves.
// Fragment rule (16x16x32): operand frag for a row-major [16][K] tile is
//   lane l -> row (l&15), k = (l>>4)*8 + j  (one 16B load);
// D: row=(l>>4)*4+r, col=l&15  [m89-verified].
__global__ __launch_bounds__(256) void mlp_mfma_kernel(
    const unsigned short* __restrict__ A, const unsigned short* __restrict__ w1b,
    const float* __restrict__ b1, const unsigned short* __restrict__ w2b,
    const float* __restrict__ b2, float* __restrict__ Y)
{
    // per-wave H tile [16][256] bf16, padded to 264 (stride 528B = 33*16B:
    // keeps 16B alignment, spreads rows across banks)
    __shared__ __align__(16) unsigned short sH[4][16][264];   // 33792 B

    int t   = threadIdx.x;
    int wid = t >> 6;
    int l   = t & 63;
    int l16 = l & 15;
    int lhi = l >> 4;         // 0..3

    int rowbase = blockIdx.x * 64 + wid * 16;
    int arow = rowbase + l16;
    if (arow >= N_NODES) arow = N_NODES - 1;   // clamp; stores are guarded

    // A fragments for 4 k-steps (live across stage 1)
    const unsigned short* Arow = A + (size_t)arow * DIM;
    bf16x8 afrag[4];
    #pragma unroll
    for (int kk = 0; kk < 4; ++kk)
        afrag[kk] = *reinterpret_cast<const bf16x8*>(Arow + kk * 32 + lhi * 8);

    // ---- stage 1: H = relu(A @ W1^T + b1) -> sH (bf16) ----
    for (int nt = 0; nt < 16; ++nt) {
        int n0 = nt * 16;
        const unsigned short* Wrow = w1b + (size_t)(n0 + l16) * DIM;
        f32x4 acc = {0.f, 0.f, 0.f, 0.f};
        #pragma unroll
        for (int kk = 0; kk < 4; ++kk) {
            bf16x8 bfrag = *reinterpret_cast<const bf16x8*>(Wrow + kk * 32 + lhi * 8);
            acc = __builtin_amdgcn_mfma_f32_16x16x32_bf16(afrag[kk], bfrag, acc, 0, 0, 0);
        }
        float bias = b1[n0 + l16];
        #pragma unroll
        for (int r = 0; r < 4; ++r) {
            float h = fmaxf(acc[r] + bias, 0.f);
            sH[wid][lhi * 4 + r][n0 + l16] = f2bf(h);
        }
    }
    // wave-private tile; MFMA + DS are wave-synchronous, compiler inserts lgkmcnt.

    // ---- stage 2: Y = H @ W2^T + b2 ----
    for (int nt = 0; nt < 8; ++nt) {
        int n0 = nt * 16;
        const unsigned short* Wrow = w2b + (size_t)(n0 + l16) * 256;
        f32x4 acc = {0.f, 0.f, 0.f, 0.f};
        #pragma unroll
        for (int kk = 0; kk < 8; ++kk) {
            bf16x8 hfrag = *reinterpret_cast<const bf16x8*>(&sH[wid][l16][kk * 32 + lhi * 8]);
            bf16x8 bfrag = *reinterpret_cast<const bf16x8*>(Wrow + kk * 32 + lhi * 8);
            acc = __builtin_amdgcn_mfma_f32_16x16x32_bf16(hfrag, bfrag, acc, 0, 0, 0);
        }
        float bias = b2[n0 + l16];
        #pragma unroll
        for (int r = 0; r < 4; ++r) {
            int grow = rowbase + lhi * 4 + r;
            if (grow < N_NODES)
                Y[(size_t)grow * DIM + n0 + l16] = acc[r] + bias;
        }
    }
}

extern "C" void kernel_launch(void* const* d_in, const int* in_sizes, int n_in,
                              void* d_out, int out_size, void* d_ws, size_t ws_size,
                              hipStream_t stream)
{
    const float* x   = (const float*)d_in[0];
    const int*  eidx = (const int*)d_in[1];
    const int*  eattr= (const int*)d_in[2];
    const float* W1  = (const float*)d_in[3];
    const float* b1  = (const float*)d_in[4];
    const float* W2  = (const float*)d_in[5];
    const float* b2  = (const float*)d_in[6];
    const float* e1  = (const float*)d_in[7];
    const float* e2  = (const float*)d_in[8];
    float* Y = (float*)d_out;

    char* ws = (char*)d_ws;
    unsigned short* outb = (unsigned short*)ws;                    // N*D bf16
    int* off             = (int*)(ws + WS_OFF_OFF);
    int* bs              = (int*)(ws + WS_BS_OFF);
    unsigned int* perm   = (unsigned int*)(ws + WS_PERM_OFF);
    unsigned short* w1b  = (unsigned short*)(ws + WS_W1B_OFF);
    unsigned short* w2b  = (unsigned short*)(ws + WS_W2B_OFF);

    zero_off_kernel <<<NB_SCAN, 256, 0, stream>>>(off);
    hist_kernel     <<<GRID_E,  256, 0, stream>>>(eidx, off);
    block_sum_kernel<<<NB_SCAN, 256, 0, stream>>>(off, bs);
    scan_bs_kernel  <<<1,       256, 0, stream>>>(bs);
    scan_off_kernel <<<NB_SCAN, 256, 0, stream>>>(off, bs);
    place_kernel    <<<GRID_E,  256, 0, stream>>>(eidx, eattr, off, perm);
    gather_kernel   <<<(N_NODES * 32 + 255) / 256, 256, 0, stream>>>(x, perm, off, e1, e2, outb);
    cvt_w_kernel    <<<128, 256, 0, stream>>>(W1, w1b, 256 * DIM);
    cvt_w_kernel    <<<128, 256, 0, stream>>>(W2, w2b, DIM * 256);
    mlp_mfma_kernel <<<(N_NODES + 63) / 64, 256, 0, stream>>>(outb, w1b, b1, w2b, b2, Y);
}

// Round 4
// 187.275 us; speedup vs baseline: 9.7004x; 1.0440x over previous
//
#include <hip/hip_runtime.h>

#define N_NODES 50000
#define N_EDGES 600000
#define DIM 128

#define NB_SCAN 196            // ceil(50000/256)
#define GRID_E 2344            // ceil(600000/256)

// ---- ws layout (bytes), all 16B-aligned ----
#define WS_OFF_OFF   0          // off[50000] int
#define WS_BS_OFF    200000     // bs[256] int
#define WS_PERM_OFF  201024     // perm[600000] u32
#define WS_XB_OFF    2601024    // xb [N*128] bf16 (12.8 MB)
#define WS_W1B_OFF   15401024   // w1b [256*128] bf16
#define WS_W2B_OFF   15466560   // w2b [128*256] bf16
#define WS_E12_OFF   15532096   // e12b [15*128] bf16

#define CVT_X4   1600000        // N*DIM/4
#define CVT_W4   8192           // 256*128/4
#define CVT_E4   480            // 15*128/4
#define CVT_TOTAL (CVT_X4 + 2*CVT_W4 + CVT_E4)

typedef __attribute__((ext_vector_type(8))) short bf16x8;
typedef __attribute__((ext_vector_type(4))) float f32x4;

__device__ __forceinline__ unsigned short f2bf(float f) {
    unsigned int b = __float_as_uint(f);
    b += 0x7FFFu + ((b >> 16) & 1u);     // round-to-nearest-even
    return (unsigned short)(b >> 16);
}
__device__ __forceinline__ float bf2f(short u) {
    return __uint_as_float(((unsigned int)(unsigned short)u) << 16);
}

__global__ __launch_bounds__(256) void zero_off_kernel(int* __restrict__ off) {
    int i = blockIdx.x * 256 + threadIdx.x;
    if (i < N_NODES) off[i] = 0;
}

__global__ __launch_bounds__(256) void hist_kernel(
    const int* __restrict__ eidx, int* __restrict__ off)
{
    int e = blockIdx.x * 256 + threadIdx.x;
    if (e < N_EDGES) atomicAdd(&off[eidx[e]], 1);
}

__global__ __launch_bounds__(256) void block_sum_kernel(
    const int* __restrict__ off, int* __restrict__ bs)
{
    __shared__ int s[256];
    int t = threadIdx.x;
    int i = blockIdx.x * 256 + t;
    s[t] = (i < N_NODES) ? off[i] : 0;
    __syncthreads();
    for (int o = 128; o > 0; o >>= 1) {
        if (t < o) s[t] += s[t + o];
        __syncthreads();
    }
    if (t == 0) bs[blockIdx.x] = s[0];
}

__global__ __launch_bounds__(256) void scan_bs_kernel(int* __restrict__ bs) {
    __shared__ int s[256];
    int t = threadIdx.x;
    s[t] = (t < NB_SCAN) ? bs[t] : 0;
    __syncthreads();
    for (int o = 1; o < 256; o <<= 1) {
        int u = (t >= o) ? s[t - o] : 0;
        __syncthreads();
        s[t] += u;
        __syncthreads();
    }
    if (t < NB_SCAN) bs[t] = s[t];
}

__global__ __launch_bounds__(256) void scan_off_kernel(
    int* __restrict__ off, const int* __restrict__ bs)
{
    __shared__ int s[256];
    int t = threadIdx.x;
    int b = blockIdx.x;
    int i = b * 256 + t;
    int v = (i < N_NODES) ? off[i] : 0;
    s[t] = v;
    __syncthreads();
    for (int o = 1; o < 256; o <<= 1) {
        int u = (t >= o) ? s[t - o] : 0;
        __syncthreads();
        s[t] += u;
        __syncthreads();
    }
    int ex = (t ? s[t - 1] : 0) + (b ? bs[b - 1] : 0);
    if (i < N_NODES) off[i] = ex;
}

__global__ __launch_bounds__(256) void place_kernel(
    const int* __restrict__ eidx, const int* __restrict__ eattr,
    int* __restrict__ off, unsigned int* __restrict__ perm)
{
    int e = blockIdx.x * 256 + threadIdx.x;
    if (e >= N_EDGES) return;
    int row = eidx[e];
    unsigned int col = (unsigned int)eidx[N_EDGES + e];
    unsigned int a0  = (unsigned int)eattr[2 * e];
    unsigned int a1  = (unsigned int)eattr[2 * e + 1];
    int pos = atomicAdd(&off[row], 1);
    perm[pos] = col | (a0 << 16) | (a1 << 19);
}

// fused conversions: x->bf16, W1->bf16, W2->bf16, e12[a0*3+a1]=e1[a0]+e2[a1] (bf16)
__global__ __launch_bounds__(256) void cvt_all_kernel(
    const float* __restrict__ x, const float* __restrict__ W1,
    const float* __restrict__ W2, const float* __restrict__ e1,
    const float* __restrict__ e2, unsigned short* __restrict__ xb,
    unsigned short* __restrict__ w1b, unsigned short* __restrict__ w2b,
    unsigned short* __restrict__ e12b)
{
    int i = blockIdx.x * 256 + threadIdx.x;
    if (i < CVT_X4) {
        float4 v = reinterpret_cast<const float4*>(x)[i];
        reinterpret_cast<ushort4*>(xb)[i] =
            make_ushort4(f2bf(v.x), f2bf(v.y), f2bf(v.z), f2bf(v.w));
    } else if (i < CVT_X4 + CVT_W4) {
        int j = i - CVT_X4;
        float4 v = reinterpret_cast<const float4*>(W1)[j];
        reinterpret_cast<ushort4*>(w1b)[j] =
            make_ushort4(f2bf(v.x), f2bf(v.y), f2bf(v.z), f2bf(v.w));
    } else if (i < CVT_X4 + 2 * CVT_W4) {
        int j = i - CVT_X4 - CVT_W4;
        float4 v = reinterpret_cast<const float4*>(W2)[j];
        reinterpret_cast<ushort4*>(w2b)[j] =
            make_ushort4(f2bf(v.x), f2bf(v.y), f2bf(v.z), f2bf(v.w));
    } else if (i < CVT_TOTAL) {
        int j = i - CVT_X4 - 2 * CVT_W4;    // [0, 480)
        int c4  = j & 31;
        int row = j >> 5;                    // a0*3+a1
        int a0 = row / 3, a1 = row - a0 * 3;
        float4 u = reinterpret_cast<const float4*>(e1 + a0 * DIM)[c4];
        float4 v = reinterpret_cast<const float4*>(e2 + a1 * DIM)[c4];
        reinterpret_cast<ushort4*>(e12b)[j] =
            make_ushort4(f2bf(u.x + v.x), f2bf(u.y + v.y),
                         f2bf(u.z + v.z), f2bf(u.w + v.w));
    }
}

// per node (16 lanes, 8 cols each): acc = x_f32 + e12[12] + sum_edges(xb[col] + e12b[er])
// writes f32 aggregate into out (= Y, consumed then overwritten by mlp kernel)
__global__ __launch_bounds__(256) void gather_kernel(
    const float* __restrict__ x, const unsigned short* __restrict__ xb,
    const unsigned short* __restrict__ e12b,
    const unsigned int* __restrict__ perm, const int* __restrict__ off,
    float* __restrict__ out)
{
    int gid = blockIdx.x * 256 + threadIdx.x;
    int g = gid >> 4;
    if (g >= N_NODES) return;
    int l = gid & 15;
    int c0 = l * 8;

    const float* xr = x + (size_t)g * DIM + c0;
    float4 s0 = *reinterpret_cast<const float4*>(xr);
    float4 s1 = *reinterpret_cast<const float4*>(xr + 4);
    bf16x8 es = *reinterpret_cast<const bf16x8*>(e12b + 12 * DIM + c0);  // a0=4,a1=0
    float acc[8] = { s0.x + bf2f(es[0]), s0.y + bf2f(es[1]),
                     s0.z + bf2f(es[2]), s0.w + bf2f(es[3]),
                     s1.x + bf2f(es[4]), s1.y + bf2f(es[5]),
                     s1.z + bf2f(es[6]), s1.w + bf2f(es[7]) };

    int start = g ? off[g - 1] : 0;
    int end   = off[g];
    for (int e = start; e < end; ++e) {
        unsigned int u = perm[e];
        int col = (int)(u & 0xFFFFu);
        int er  = (int)((u >> 16) & 7u) * 3 + (int)(u >> 19);
        bf16x8 xv = *reinterpret_cast<const bf16x8*>(xb + (size_t)col * DIM + c0);
        bf16x8 ev = *reinterpret_cast<const bf16x8*>(e12b + er * DIM + c0);
        #pragma unroll
        for (int j = 0; j < 8; ++j) acc[j] += bf2f(xv[j]) + bf2f(ev[j]);
    }

    float* op = out + (size_t)g * DIM + c0;
    *reinterpret_cast<float4*>(op)     = make_float4(acc[0], acc[1], acc[2], acc[3]);
    *reinterpret_cast<float4*>(op + 4) = make_float4(acc[4], acc[5], acc[6], acc[7]);
}

// Fused MLP via MFMA: Y = relu(A @ W1^T + b1) @ W2^T + b2.  A aliases Y (f32).
// 32 rows/block, 4 waves: wave (pair,sub); the two waves of a pair co-own one
// 16-row tile (sub splits hidden tiles in stage 1 and d-tiles in stage 2).
// 16x16x32 frag: lane l -> row (l&15), k=(l>>4)*8+j ; D: row=(l>>4)*4+r, col=l&15.
__global__ __launch_bounds__(256) void mlp_mfma_kernel(
    const float* __restrict__ A, const unsigned short* __restrict__ w1b,
    const float* __restrict__ b1, const unsigned short* __restrict__ w2b,
    const float* __restrict__ b2, float* __restrict__ Y)
{
    __shared__ __align__(16) unsigned short sH[2][16][264];   // 16896 B

    int t    = threadIdx.x;
    int wid  = t >> 6;
    int pair = wid >> 1;      // row tile within block
    int sub  = wid & 1;       // work split within pair
    int l    = t & 63;
    int l16  = l & 15;
    int lhi  = l >> 4;        // 0..3

    int rowbase = blockIdx.x * 32 + pair * 16;
    int arow = rowbase + l16;
    if (arow >= N_NODES) arow = N_NODES - 1;   // clamped reads stay in-block

    // A row slice f32 -> 4 bf16x8 fragments
    const float* Arow = A + (size_t)arow * DIM;
    bf16x8 afrag[4];
    #pragma unroll
    for (int kk = 0; kk < 4; ++kk) {
        const float* p = Arow + kk * 32 + lhi * 8;
        float4 u0 = *reinterpret_cast<const float4*>(p);
        float4 u1 = *reinterpret_cast<const float4*>(p + 4);
        bf16x8 f;
        f[0] = (short)f2bf(u0.x); f[1] = (short)f2bf(u0.y);
        f[2] = (short)f2bf(u0.z); f[3] = (short)f2bf(u0.w);
        f[4] = (short)f2bf(u1.x); f[5] = (short)f2bf(u1.y);
        f[6] = (short)f2bf(u1.z); f[7] = (short)f2bf(u1.w);
        afrag[kk] = f;
    }

    // ---- stage 1: H = relu(A @ W1^T + b1) -> sH (bf16); 8 hidden tiles/wave ----
    for (int nt = sub * 8; nt < sub * 8 + 8; ++nt) {
        int n0 = nt * 16;
        const unsigned short* Wrow = w1b + (size_t)(n0 + l16) * DIM;
        f32x4 acc = {0.f, 0.f, 0.f, 0.f};
        #pragma unroll
        for (int kk = 0; kk < 4; ++kk) {
            bf16x8 bfrag = *reinterpret_cast<const bf16x8*>(Wrow + kk * 32 + lhi * 8);
            acc = __builtin_amdgcn_mfma_f32_16x16x32_bf16(afrag[kk], bfrag, acc, 0, 0, 0);
        }
        float bias = b1[n0 + l16];
        #pragma unroll
        for (int r = 0; r < 4; ++r) {
            float h = fmaxf(acc[r] + bias, 0.f);
            sH[pair][lhi * 4 + r][n0 + l16] = f2bf(h);
        }
    }
    __syncthreads();

    // ---- stage 2: Y = H @ W2^T + b2; 4 d-tiles/wave, full K=256 ----
    for (int nt = sub * 4; nt < sub * 4 + 4; ++nt) {
        int n0 = nt * 16;
        const unsigned short* Wrow = w2b + (size_t)(n0 + l16) * 256;
        f32x4 acc = {0.f, 0.f, 0.f, 0.f};
        #pragma unroll
        for (int kk = 0; kk < 8; ++kk) {
            bf16x8 hfrag = *reinterpret_cast<const bf16x8*>(&sH[pair][l16][kk * 32 + lhi * 8]);
            bf16x8 bfrag = *reinterpret_cast<const bf16x8*>(Wrow + kk * 32 + lhi * 8);
            acc = __builtin_amdgcn_mfma_f32_16x16x32_bf16(hfrag, bfrag, acc, 0, 0, 0);
        }
        float bias = b2[n0 + l16];
        #pragma unroll
        for (int r = 0; r < 4; ++r) {
            int grow = rowbase + lhi * 4 + r;
            if (grow < N_NODES)
                Y[(size_t)grow * DIM + n0 + l16] = acc[r] + bias;
        }
    }
}

extern "C" void kernel_launch(void* const* d_in, const int* in_sizes, int n_in,
                              void* d_out, int out_size, void* d_ws, size_t ws_size,
                              hipStream_t stream)
{
    const float* x   = (const float*)d_in[0];
    const int*  eidx = (const int*)d_in[1];
    const int*  eattr= (const int*)d_in[2];
    const float* W1  = (const float*)d_in[3];
    const float* b1  = (const float*)d_in[4];
    const float* W2  = (const float*)d_in[5];
    const float* b2  = (const float*)d_in[6];
    const float* e1  = (const float*)d_in[7];
    const float* e2  = (const float*)d_in[8];
    float* Y = (float*)d_out;

    char* ws = (char*)d_ws;
    int* off             = (int*)(ws + WS_OFF_OFF);
    int* bs              = (int*)(ws + WS_BS_OFF);
    unsigned int* perm   = (unsigned int*)(ws + WS_PERM_OFF);
    unsigned short* xb   = (unsigned short*)(ws + WS_XB_OFF);
    unsigned short* w1b  = (unsigned short*)(ws + WS_W1B_OFF);
    unsigned short* w2b  = (unsigned short*)(ws + WS_W2B_OFF);
    unsigned short* e12b = (unsigned short*)(ws + WS_E12_OFF);

    zero_off_kernel <<<NB_SCAN, 256, 0, stream>>>(off);
    hist_kernel     <<<GRID_E,  256, 0, stream>>>(eidx, off);
    block_sum_kernel<<<NB_SCAN, 256, 0, stream>>>(off, bs);
    scan_bs_kernel  <<<1,       256, 0, stream>>>(bs);
    scan_off_kernel <<<NB_SCAN, 256, 0, stream>>>(off, bs);
    place_kernel    <<<GRID_E,  256, 0, stream>>>(eidx, eattr, off, perm);
    cvt_all_kernel  <<<(CVT_TOTAL + 255) / 256, 256, 0, stream>>>(
                        x, W1, W2, e1, e2, xb, w1b, w2b, e12b);
    gather_kernel   <<<(N_NODES * 16 + 255) / 256, 256, 0, stream>>>(
                        x, xb, e12b, perm, off, Y);
    mlp_mfma_kernel <<<(N_NODES + 31) / 32, 256, 0, stream>>>(Y, w1b, b1, w2b, b2, Y);
}